// Round 12
// baseline (838.723 us; speedup 1.0000x reference)
//
#include <hip/hip_runtime.h>

#define N_NODES 8192
#define N_EDGES 262144
#define SLOPE 0.25f

typedef __attribute__((ext_vector_type(8))) short bf16x8;
typedef __attribute__((ext_vector_type(4))) float f32x4;

__device__ __forceinline__ float lrelu(float x) { return x >= 0.f ? x : SLOPE * x; }

__device__ __forceinline__ unsigned short bf16_rne(float x) {
    unsigned u = __float_as_uint(x);
    return (unsigned short)((u + 0x7FFFu + ((u >> 16) & 1u)) >> 16);
}
__device__ __forceinline__ float bf2f(unsigned short h) {
    return __uint_as_float(((unsigned)h) << 16);
}
__device__ __forceinline__ bf16x8 pack8(const float4& a, const float4& b) {
    bf16x8 r;
    r[0] = (short)bf16_rne(a.x); r[1] = (short)bf16_rne(a.y);
    r[2] = (short)bf16_rne(a.z); r[3] = (short)bf16_rne(a.w);
    r[4] = (short)bf16_rne(b.x); r[5] = (short)bf16_rne(b.y);
    r[6] = (short)bf16_rne(b.z); r[7] = (short)bf16_rne(b.w);
    return r;
}

#define GLDS16(g, l)                                                              \
    __builtin_amdgcn_global_load_lds((const __attribute__((address_space(1))) void*)(g), \
                                     (__attribute__((address_space(3))) void*)(l), 16, 0, 0)

// ---------------- batched W [K,N] f32 -> WT bf16 [N,K] (transpose + round) ----------------
struct TransB { const float* W[4]; unsigned short* Th[4]; int K[4]; int N[4]; };

__global__ __launch_bounds__(256) void tsplit(TransB tb) {
    const int z = blockIdx.z;
    const int K = tb.K[z], N = tb.N[z];
    const int k0 = blockIdx.x * 32, n0 = blockIdx.y * 32;
    if (k0 >= K || n0 >= N) return;
    __shared__ float t[32][33];
    const int tx = threadIdx.x & 31, ty = threadIdx.x >> 5;
    const float* W = tb.W[z];
#pragma unroll
    for (int i = 0; i < 32; i += 8)
        t[ty + i][tx] = W[(size_t)(k0 + ty + i) * N + n0 + tx];
    __syncthreads();
#pragma unroll
    for (int i = 0; i < 32; i += 8) {
        const int n = ty + i;
        tb.Th[z][(size_t)(n0 + n) * K + k0 + tx] = bf16_rne(t[tx][n]);
    }
}

// ---------------- batched GEMM: C(bf16) = A @ B(bf16)^T, A direct-to-register ----------------
// Block 64(M) x NF*32(N); 4 waves (2x2); wave tile 32 x NF*16.
// A: lane-private frags loaded straight from global (f32+cvt if AF32, bf16 else),
//    ping-pong reg sets, issued 2 K-steps ahead. No A LDS, no ds_write.
// B: global_load_lds, depth-2, 3 LDS buffers, counted vmcnt (never 0 in main loop).
//    LDS [rows][64B], granule (row,s), source k-group kg = s ^ ((row>>1)&3) (0-conflict, R6+).
struct GemmB {
    const void* A[4];             // [M,K] f32 (AF32=1) or bf16 (AF32=0)
    const unsigned short* Bh[4];  // [N,K] bf16
    unsigned short* C[4];         // [M,N] bf16
    int K[4];
    int NT[4];                    // N / (NF*32) tiles
};

template <int NF, int AF32>
__global__ __launch_bounds__(256, 3) void gemm_bf16s(GemmB gb) {
    constexpr int BGR = NF / 2;  // B glds issues per thread per stage
    // bijective XCD-chunked swizzle (nwg divisible by 8 in all launches here)
    const int nwg = gridDim.x * gridDim.y * gridDim.z;
    int id = (blockIdx.z * gridDim.y + blockIdx.y) * gridDim.x + blockIdx.x;
    const int cpx = nwg >> 3;
    id = (id & 7) * cpx + (id >> 3);
    // by (N-tile) fastest: consecutive work-ids share the same A M-panel (L2 reuse)
    const int by = id % gridDim.y;
    const int rest = id / gridDim.y;
    const int bx = rest % gridDim.x;
    const int z = rest / gridDim.x;

    const int nt = gb.NT[z];
    if (by >= nt) return;
    const int K = gb.K[z];
    const int N = nt * (NF * 32);
    const float* __restrict__ Af = (const float*)gb.A[z];
    const unsigned short* __restrict__ Ab = (const unsigned short*)gb.A[z];
    const unsigned short* __restrict__ Bh = gb.Bh[z];
    unsigned short* __restrict__ C = gb.C[z];

    __shared__ unsigned short Bs[3 * NF * 1024];   // 3 x (NF*2 KB)
    const int tid = threadIdx.x;
    const int w = tid >> 6, lane = tid & 63;
    const int wm = w >> 1, wn = w & 1;
    const int m15 = lane & 15, kq = lane >> 4;
    const int bm0 = bx * 64, bn0 = by * (NF * 32);

    auto stageB = [&](int buf, int kt) {
        const int k0 = kt << 5;
#pragma unroll
        for (int i = 0; i < BGR; ++i) {
            const int f = (w * BGR + i) * 64 + lane;
            const int row = f >> 2, s = f & 3;
            const int kg = s ^ ((row >> 1) & 3);
            GLDS16(Bh + (size_t)(bn0 + row) * K + k0 + kg * 8,
                   &Bs[buf * (NF * 1024) + (w * BGR + i) * 512]);
        }
    };
    // A issue: lane-private fragment rows, cols kq*8..+7 of the K-step
    auto issueAf = [&](float4 (&ar)[2][2], int kt) {
        const int k0 = kt << 5;
#pragma unroll
        for (int mf = 0; mf < 2; ++mf) {
            const float* src = Af + (size_t)(bm0 + wm * 32 + mf * 16 + m15) * K + k0 + kq * 8;
            ar[mf][0] = *reinterpret_cast<const float4*>(src);
            ar[mf][1] = *reinterpret_cast<const float4*>(src + 4);
        }
    };
    auto issueAb = [&](bf16x8 (&ar)[2], int kt) {
        const int k0 = kt << 5;
#pragma unroll
        for (int mf = 0; mf < 2; ++mf)
            ar[mf] = *reinterpret_cast<const bf16x8*>(
                Ab + (size_t)(bm0 + wm * 32 + mf * 16 + m15) * K + k0 + kq * 8);
    };

    f32x4 acc[2][NF];
#pragma unroll
    for (int mf = 0; mf < 2; ++mf)
#pragma unroll
        for (int nf = 0; nf < NF; ++nf) acc[mf][nf] = (f32x4){0.f, 0.f, 0.f, 0.f};

    const int nk = K >> 5;  // even, >= 8 in all uses
    float4 aEf[2][2], aOf[2][2];
    bf16x8 aEb[2], aOb[2];

    if constexpr (AF32) {
        stageB(0, 0); issueAf(aEf, 0);
        stageB(1, 1); issueAf(aOf, 1);
    } else {
        stageB(0, 0); issueAb(aEb, 0);
        stageB(1, 1); issueAb(aOb, 1);
    }

    auto body = [&](int t, float4 (&arf)[2][2], bf16x8 (&arb)[2]) {
        const int cb = t % 3;
        // stage B(t+2), then wait for B(t): ops issued after B(t) = A(t)+B(t+1)+A(t+1)+B(t+2)
        if (t + 2 < nk) {
            stageB((t + 2) % 3, t + 2);
            if constexpr (AF32) asm volatile("s_waitcnt vmcnt(16)" ::: "memory");
            else asm volatile("s_waitcnt vmcnt(12)" ::: "memory");
        } else if (t + 1 < nk) {
            if constexpr (AF32) asm volatile("s_waitcnt vmcnt(12)" ::: "memory");
            else asm volatile("s_waitcnt vmcnt(8)" ::: "memory");
        } else {
            asm volatile("s_waitcnt vmcnt(0)" ::: "memory");
        }
        __builtin_amdgcn_s_barrier();        // B(t) visible to all waves
        __builtin_amdgcn_sched_barrier(0);

        // materialize A frags (compiler auto-waits its own loads), refill set for t+2
        bf16x8 a[2];
        if constexpr (AF32) {
            a[0] = pack8(arf[0][0], arf[0][1]);
            a[1] = pack8(arf[1][0], arf[1][1]);
            if (t + 2 < nk) issueAf(arf, t + 2);
        } else {
            a[0] = arb[0];
            a[1] = arb[1];
            if (t + 2 < nk) issueAb(arb, t + 2);
        }

        bf16x8 b[NF];
#pragma unroll
        for (int nf = 0; nf < NF; ++nf) {
            const int r = wn * (NF * 16) + nf * 16 + m15;
            b[nf] = *reinterpret_cast<const bf16x8*>(
                &Bs[cb * (NF * 1024) + r * 32 + ((kq ^ ((r >> 1) & 3)) << 3)]);
        }
        __builtin_amdgcn_s_setprio(1);
#pragma unroll
        for (int mf = 0; mf < 2; ++mf)
#pragma unroll
            for (int nf = 0; nf < NF; ++nf)
                acc[mf][nf] = __builtin_amdgcn_mfma_f32_16x16x32_bf16(a[mf], b[nf], acc[mf][nf], 0, 0, 0);
        __builtin_amdgcn_s_setprio(0);

        __builtin_amdgcn_s_barrier();        // all waves done reading buf cb before its reuse
    };

    for (int t = 0; t < nk; t += 2) {
        body(t, aEf, aEb);
        body(t + 1, aOf, aOb);
    }

    const int cr = kq * 4, cc = m15;
#pragma unroll
    for (int mf = 0; mf < 2; ++mf)
#pragma unroll
        for (int nf = 0; nf < NF; ++nf)
#pragma unroll
            for (int j = 0; j < 4; ++j)
                C[(size_t)(bm0 + wm * 32 + mf * 16 + cr + j) * N + bn0 + wn * (NF * 16) + nf * 16 + cc] =
                    bf16_rne(acc[mf][nf][j]);
}

// ---------------- batched CSR build (4 graphs), packed (col,val) edges ----------------
struct GraphPtrs {
    const int* r[4];
    const int* c[4];
    const float* v[4];
};

__global__ __launch_bounds__(256) void hist4(GraphPtrs p, int* __restrict__ cnt4) {
    const int g = blockIdx.y;
    const int e = blockIdx.x * 256 + threadIdx.x;
    atomicAdd(&cnt4[g * N_NODES + p.r[g][e]], 1);
}

__global__ __launch_bounds__(256) void scan4(const int* __restrict__ cnt4,
                                             int* __restrict__ rs4,
                                             int* __restrict__ cur4) {
    const int g = blockIdx.x;
    const int* cnt = cnt4 + g * N_NODES;
    int* row_start = rs4 + (size_t)g * (N_NODES + 1);
    int* cursor = cur4 + g * N_NODES;
    __shared__ int ssum[256];
    const int t = threadIdx.x;
    int local[32];
    int s = 0;
#pragma unroll
    for (int j = 0; j < 32; ++j) { local[j] = cnt[t * 32 + j]; s += local[j]; }
    ssum[t] = s;
    __syncthreads();
    for (int off = 1; off < 256; off <<= 1) {
        const int v = ssum[t];
        const int add = (t >= off) ? ssum[t - off] : 0;
        __syncthreads();
        ssum[t] = v + add;
        __syncthreads();
    }
    int run = (t == 0) ? 0 : ssum[t - 1];
#pragma unroll
    for (int j = 0; j < 32; ++j) {
        row_start[t * 32 + j] = run;
        cursor[t * 32 + j] = run;
        run += local[j];
    }
    if (t == 255) row_start[N_NODES] = run;
}

__global__ __launch_bounds__(256) void scatter4(GraphPtrs p, int* __restrict__ cur4,
                                                unsigned long long* __restrict__ pe4) {
    const int g = blockIdx.y;
    const int e = blockIdx.x * 256 + threadIdx.x;
    const int r = p.r[g][e];
    const int pos = atomicAdd(&cur4[g * N_NODES + r], 1);
    pe4[(size_t)g * N_EDGES + pos] =
        (unsigned long long)(unsigned)p.c[g][e] |
        ((unsigned long long)__float_as_uint(p.v[g][e]) << 32);
}

// ---------------- gather SpMM layer 1: XCD-partitioned, all 4 branches ----------------
struct SpmmB {
    const int* rs[4];
    const unsigned long long* pe[4];
    const unsigned short* Y[4];   // bf16
    const float* bi[4];
    unsigned short* H[4];
    int nc[4];
};

__global__ __launch_bounds__(256) void spmm_h1x(SpmmB sb) {
    const int id = blockIdx.x;              // 8192 blocks
    const int xcd = id & 7;
    const int z = xcd >> 1;                  // branch
    const int rb = ((id >> 3) << 1) + (id & 1);  // row-block 0..2047 within branch
    const int row = rb * 4 + (threadIdx.x >> 6);
    const int lane = threadIdx.x & 63;
    const int nc = sb.nc[z];
    const int* rs = sb.rs[z];
    const int s = rs[row], e1 = rs[row + 1];
    const unsigned long long* pe = sb.pe[z];
    const unsigned short* Y = sb.Y[z];
    const float* bi = sb.bi[z];

    if (nc == 512) {
        const int base = lane * 8;
        float acc[8];
#pragma unroll
        for (int j = 0; j < 8; ++j) acc[j] = 0.f;
        for (int e = s; e < e1; ++e) {
            const unsigned long long ev = pe[e];
            const float v = __uint_as_float((unsigned)(ev >> 32));
            const bf16x8 raw = *reinterpret_cast<const bf16x8*>(
                Y + (size_t)(unsigned)ev * 512 + base);
#pragma unroll
            for (int j = 0; j < 8; ++j)
                acc[j] = fmaf(v, bf2f((unsigned short)raw[j]), acc[j]);
        }
        bf16x8 vh;
#pragma unroll
        for (int j = 0; j < 8; ++j) vh[j] = (short)bf16_rne(lrelu(acc[j] + bi[base + j]));
        *reinterpret_cast<bf16x8*>(sb.H[z] + (size_t)row * 512 + base) = vh;
    } else {
        const int base = lane * 4;
        float acc[4];
#pragma unroll
        for (int j = 0; j < 4; ++j) acc[j] = 0.f;
        for (int e = s; e < e1; ++e) {
            const unsigned long long ev = pe[e];
            const float v = __uint_as_float((unsigned)(ev >> 32));
            const ushort4 raw = *reinterpret_cast<const ushort4*>(
                Y + (size_t)(unsigned)ev * 256 + base);
            acc[0] = fmaf(v, bf2f(raw.x), acc[0]);
            acc[1] = fmaf(v, bf2f(raw.y), acc[1]);
            acc[2] = fmaf(v, bf2f(raw.z), acc[2]);
            acc[3] = fmaf(v, bf2f(raw.w), acc[3]);
        }
        ushort4 vh;
        vh.x = bf16_rne(lrelu(acc[0] + bi[base + 0]));
        vh.y = bf16_rne(lrelu(acc[1] + bi[base + 1]));
        vh.z = bf16_rne(lrelu(acc[2] + bi[base + 2]));
        vh.w = bf16_rne(lrelu(acc[3] + bi[base + 3]));
        *reinterpret_cast<ushort4*>(sb.H[z] + (size_t)row * 256 + base) = vh;
    }
}

// tier-2 single-branch layer-1 spmm
template <int NC>
__global__ __launch_bounds__(256) void spmm_h1(const int* __restrict__ rs,
                                               const unsigned long long* __restrict__ pe,
                                               const unsigned short* __restrict__ Y,
                                               const float* __restrict__ bi,
                                               unsigned short* __restrict__ Hd) {
    constexpr int PL = NC / 64;
    const int row = (blockIdx.x * 256 + threadIdx.x) >> 6;
    const int lane = threadIdx.x & 63;
    const int s = rs[row], e1 = rs[row + 1];
    const int base = lane * PL;
    float acc[PL];
#pragma unroll
    for (int j = 0; j < PL; ++j) acc[j] = 0.f;
    for (int e = s; e < e1; ++e) {
        const unsigned long long ev = pe[e];
        const float v = __uint_as_float((unsigned)(ev >> 32));
        const unsigned short* y = Y + (size_t)(unsigned)ev * NC + base;
        if constexpr (PL == 8) {
            const bf16x8 raw = *reinterpret_cast<const bf16x8*>(y);
#pragma unroll
            for (int j = 0; j < 8; ++j)
                acc[j] = fmaf(v, bf2f((unsigned short)raw[j]), acc[j]);
        } else {
            const ushort4 raw = *reinterpret_cast<const ushort4*>(y);
            acc[0] = fmaf(v, bf2f(raw.x), acc[0]);
            acc[1] = fmaf(v, bf2f(raw.y), acc[1]);
            acc[2] = fmaf(v, bf2f(raw.z), acc[2]);
            acc[3] = fmaf(v, bf2f(raw.w), acc[3]);
        }
    }
    unsigned short* H = Hd + (size_t)row * NC + base;
    if constexpr (PL == 8) {
        bf16x8 vh;
#pragma unroll
        for (int j = 0; j < 8; ++j) vh[j] = (short)bf16_rne(lrelu(acc[j] + bi[base + j]));
        *reinterpret_cast<bf16x8*>(H) = vh;
    } else {
        ushort4 vh;
        vh.x = bf16_rne(lrelu(acc[0] + bi[base + 0]));
        vh.y = bf16_rne(lrelu(acc[1] + bi[base + 1]));
        vh.z = bf16_rne(lrelu(acc[2] + bi[base + 2]));
        vh.w = bf16_rne(lrelu(acc[3] + bi[base + 3]));
        *reinterpret_cast<ushort4*>(H) = vh;
    }
}

// ---------------- fused output: out[row] = 0.25 * sum_b lrelu(spmm_b(Y2_b)[row] + b2_b) ----------------
struct Out4 { const float* b2[4]; };

__global__ __launch_bounds__(256) void spmm_out4(const int* __restrict__ rs4,
                                                 const unsigned long long* __restrict__ pe4,
                                                 const unsigned short* __restrict__ Y2all,
                                                 Out4 ob, float* __restrict__ out) {
    const int row = (blockIdx.x * 256 + threadIdx.x) >> 6;
    const int lane = threadIdx.x & 63;
    const int base = lane * 2;
    float r0 = 0.f, r1 = 0.f;
#pragma unroll
    for (int b = 0; b < 4; ++b) {
        const int* rs = rs4 + (size_t)b * (N_NODES + 1);
        const int s = rs[row], e1 = rs[row + 1];
        const unsigned long long* pe = pe4 + (size_t)b * N_EDGES;
        const unsigned short* Y = Y2all + (size_t)b * N_NODES * 128;
        float a0 = 0.f, a1 = 0.f;
        for (int e = s; e < e1; ++e) {
            const unsigned long long ev = pe[e];
            const float v = __uint_as_float((unsigned)(ev >> 32));
            const unsigned u = *reinterpret_cast<const unsigned*>(
                Y + (size_t)(unsigned)ev * 128 + base);
            a0 = fmaf(v, __uint_as_float(u << 16), a0);
            a1 = fmaf(v, __uint_as_float(u & 0xFFFF0000u), a1);
        }
        const float* bi = ob.b2[b];
        r0 += lrelu(a0 + bi[base]);
        r1 += lrelu(a1 + bi[base + 1]);
    }
    *reinterpret_cast<float2*>(out + (size_t)row * 128 + base) =
        make_float2(0.25f * r0, 0.25f * r1);
}

// tier-2 single-branch output accumulate
__global__ __launch_bounds__(256) void spmm_out1(const int* __restrict__ rs,
                                                 const unsigned long long* __restrict__ pe,
                                                 const unsigned short* __restrict__ Y,
                                                 const float* __restrict__ bias,
                                                 float* __restrict__ out, int first) {
    const int row = (blockIdx.x * 256 + threadIdx.x) >> 6;
    const int lane = threadIdx.x & 63;
    const int base = lane * 2;
    const int s = rs[row], e1 = rs[row + 1];
    float a0 = 0.f, a1 = 0.f;
    for (int e = s; e < e1; ++e) {
        const unsigned long long ev = pe[e];
        const float v = __uint_as_float((unsigned)(ev >> 32));
        const unsigned u = *reinterpret_cast<const unsigned*>(
            Y + (size_t)(unsigned)ev * 128 + base);
        a0 = fmaf(v, __uint_as_float(u << 16), a0);
        a1 = fmaf(v, __uint_as_float(u & 0xFFFF0000u), a1);
    }
    float r0 = 0.25f * lrelu(a0 + bias[base]);
    float r1 = 0.25f * lrelu(a1 + bias[base + 1]);
    float* o = out + (size_t)row * 128 + base;
    if (!first) {
        const float2 p = *reinterpret_cast<const float2*>(o);
        r0 += p.x;
        r1 += p.y;
    }
    *reinterpret_cast<float2*>(o) = make_float2(r0, r1);
}

extern "C" void kernel_launch(void* const* d_in, const int* in_sizes, int n_in,
                              void* d_out, int out_size, void* d_ws, size_t ws_size,
                              hipStream_t stream) {
    const float* X[4] = {(const float*)d_in[0], (const float*)d_in[1],
                         (const float*)d_in[2], (const float*)d_in[3]};
    GraphPtrs gp;
    for (int b = 0; b < 4; ++b) {
        gp.r[b] = (const int*)d_in[4 + 3 * b];
        gp.c[b] = (const int*)d_in[5 + 3 * b];
        gp.v[b] = (const float*)d_in[6 + 3 * b];
    }
    const float *w1[4], *b1[4], *w2[4], *b2[4];
    for (int b = 0; b < 4; ++b) {
        w1[b] = (const float*)d_in[16 + 4 * b + 0];
        b1[b] = (const float*)d_in[16 + 4 * b + 1];
        w2[b] = (const float*)d_in[16 + 4 * b + 2];
        b2[b] = (const float*)d_in[16 + 4 * b + 3];
    }
    const int din[4] = {4096, 4096, 4096, 1024};
    const int dh[4] = {512, 512, 512, 256};
    float* out = (float*)d_out;

    char* wsc = (char*)d_ws;
    size_t off = 0;
    auto carve = [&](size_t bytes) {
        void* p = wsc + off;
        off += (bytes + 255) & ~(size_t)255;
        return p;
    };
    int* cnt4 = (int*)carve((size_t)4 * N_NODES * 4);
    int* rs4 = (int*)carve((size_t)4 * (N_NODES + 1) * 4);
    int* cur4 = (int*)carve((size_t)4 * N_NODES * 4);
    unsigned long long* pe4 = (unsigned long long*)carve((size_t)4 * N_EDGES * 8);

    size_t tier1_base = off;
    unsigned short *W1h[4], *W2h[4], *Y1[4], *H1[4];
    for (int b = 0; b < 4; ++b) W1h[b] = (unsigned short*)carve((size_t)dh[b] * din[b] * 2);
    for (int b = 0; b < 4; ++b) W2h[b] = (unsigned short*)carve((size_t)128 * dh[b] * 2);
    for (int b = 0; b < 4; ++b) Y1[b] = (unsigned short*)carve((size_t)N_NODES * dh[b] * 2);
    for (int b = 0; b < 4; ++b) H1[b] = (unsigned short*)carve((size_t)N_NODES * dh[b] * 2);
    unsigned short* Y2all = (unsigned short*)carve((size_t)4 * N_NODES * 128 * 2);
    const bool tier1 = (off <= ws_size);
    unsigned short* Y2s[4];
    if (tier1) {
        for (int b = 0; b < 4; ++b) Y2s[b] = Y2all + (size_t)b * N_NODES * 128;
    } else {
        off = tier1_base;
        unsigned short* w1h = (unsigned short*)carve((size_t)512 * 4096 * 2);
        unsigned short* w2h = (unsigned short*)carve((size_t)128 * 512 * 2);
        unsigned short* y1 = (unsigned short*)carve((size_t)N_NODES * 512 * 2);
        unsigned short* h1 = (unsigned short*)carve((size_t)N_NODES * 512 * 2);
        unsigned short* y2 = (unsigned short*)carve((size_t)N_NODES * 128 * 2);
        for (int b = 0; b < 4; ++b) {
            W1h[b] = w1h; W2h[b] = w2h;
            Y1[b] = y1; H1[b] = h1; Y2s[b] = y2;
        }
    }

    // ---- batched CSR build ----
    hipMemsetAsync(cnt4, 0, (size_t)4 * N_NODES * sizeof(int), stream);
    {
        dim3 g(N_EDGES / 256, 4);
        hist4<<<g, 256, 0, stream>>>(gp, cnt4);
        scan4<<<4, 256, 0, stream>>>(cnt4, rs4, cur4);
        scatter4<<<g, 256, 0, stream>>>(gp, cur4, pe4);
    }

    if (tier1) {
        TransB t1;
        for (int b = 0; b < 4; ++b) {
            t1.W[b] = w1[b]; t1.Th[b] = W1h[b];
            t1.K[b] = din[b]; t1.N[b] = dh[b];
        }
        tsplit<<<dim3(128, 16, 4), 256, 0, stream>>>(t1);

        GemmB g1;
        for (int b = 0; b < 4; ++b) {
            g1.A[b] = X[b]; g1.Bh[b] = W1h[b];
            g1.C[b] = Y1[b]; g1.K[b] = din[b]; g1.NT[b] = dh[b] / 256;
        }
        gemm_bf16s<8, 1><<<dim3(128, 2, 4), 256, 0, stream>>>(g1);

        SpmmB s1;
        for (int b = 0; b < 4; ++b) {
            s1.rs[b] = rs4 + (size_t)b * (N_NODES + 1);
            s1.pe[b] = pe4 + (size_t)b * N_EDGES;
            s1.Y[b] = Y1[b]; s1.bi[b] = b1[b]; s1.H[b] = H1[b];
            s1.nc[b] = dh[b];
        }
        spmm_h1x<<<8192, 256, 0, stream>>>(s1);

        TransB t2;
        for (int b = 0; b < 4; ++b) {
            t2.W[b] = w2[b]; t2.Th[b] = W2h[b];
            t2.K[b] = dh[b]; t2.N[b] = 128;
        }
        tsplit<<<dim3(16, 4, 4), 256, 0, stream>>>(t2);

        GemmB g2;
        for (int b = 0; b < 4; ++b) {
            g2.A[b] = H1[b]; g2.Bh[b] = W2h[b];
            g2.C[b] = Y2s[b]; g2.K[b] = dh[b]; g2.NT[b] = 1;
        }
        gemm_bf16s<4, 0><<<dim3(128, 1, 4), 256, 0, stream>>>(g2);

        Out4 ob;
        for (int b = 0; b < 4; ++b) ob.b2[b] = b2[b];
        spmm_out4<<<N_NODES / 4, 256, 0, stream>>>(rs4, pe4, Y2all, ob, out);
    } else {
        for (int b = 0; b < 4; ++b) {
            TransB t1;
            t1.W[0] = w1[b]; t1.Th[0] = W1h[b];
            t1.K[0] = din[b]; t1.N[0] = dh[b];
            tsplit<<<dim3(din[b] / 32, dh[b] / 32, 1), 256, 0, stream>>>(t1);
            GemmB g1;
            g1.A[0] = X[b]; g1.Bh[0] = W1h[b];
            g1.C[0] = Y1[b]; g1.K[0] = din[b]; g1.NT[0] = dh[b] / 256;
            gemm_bf16s<8, 1><<<dim3(128, dh[b] / 256 ? dh[b] / 256 : 1, 1), 256, 0, stream>>>(g1);
            if (dh[b] == 512)
                spmm_h1<512><<<N_NODES / 4, 256, 0, stream>>>(
                    rs4 + (size_t)b * (N_NODES + 1), pe4 + (size_t)b * N_EDGES,
                    Y1[b], b1[b], H1[b]);
            else
                spmm_h1<256><<<N_NODES / 4, 256, 0, stream>>>(
                    rs4 + (size_t)b * (N_NODES + 1), pe4 + (size_t)b * N_EDGES,
                    Y1[b], b1[b], H1[b]);
            TransB t2;
            t2.W[0] = w2[b]; t2.Th[0] = W2h[b];
            t2.K[0] = dh[b]; t2.N[0] = 128;
            tsplit<<<dim3(dh[b] / 32, 4, 1), 256, 0, stream>>>(t2);
            GemmB g2;
            g2.A[0] = H1[b]; g2.Bh[0] = W2h[b];
            g2.C[0] = Y2s[b]; g2.K[0] = dh[b]; g2.NT[0] = 1;
            gemm_bf16s<4, 0><<<dim3(128, 1, 1), 256, 0, stream>>>(g2);
            spmm_out1<<<N_NODES / 4, 256, 0, stream>>>(
                rs4 + (size_t)b * (N_NODES + 1), pe4 + (size_t)b * N_EDGES,
                Y2s[b], b2[b], out, b == 0);
        }
    }
}

// Round 13
// 533.901 us; speedup vs baseline: 1.5709x; 1.5709x over previous
//
#include <hip/hip_runtime.h>

#define N_NODES 8192
#define N_EDGES 262144
#define SLOPE 0.25f

typedef __attribute__((ext_vector_type(8))) short bf16x8;
typedef __attribute__((ext_vector_type(4))) float f32x4;

__device__ __forceinline__ float lrelu(float x) { return x >= 0.f ? x : SLOPE * x; }

__device__ __forceinline__ unsigned short bf16_rne(float x) {
    unsigned u = __float_as_uint(x);
    return (unsigned short)((u + 0x7FFFu + ((u >> 16) & 1u)) >> 16);
}
__device__ __forceinline__ float bf2f(unsigned short h) {
    return __uint_as_float(((unsigned)h) << 16);
}
__device__ __forceinline__ bf16x8 pack8(const float4& a, const float4& b) {
    bf16x8 r;
    r[0] = (short)bf16_rne(a.x); r[1] = (short)bf16_rne(a.y);
    r[2] = (short)bf16_rne(a.z); r[3] = (short)bf16_rne(a.w);
    r[4] = (short)bf16_rne(b.x); r[5] = (short)bf16_rne(b.y);
    r[6] = (short)bf16_rne(b.z); r[7] = (short)bf16_rne(b.w);
    return r;
}

#define GLDS16(g, l)                                                              \
    __builtin_amdgcn_global_load_lds((const __attribute__((address_space(1))) void*)(g), \
                                     (__attribute__((address_space(3))) void*)(l), 16, 0, 0)

// ---------------- batched W [K,N] f32 -> WT bf16 [N,K] (transpose + round), 8 slots ----------------
struct TransB8 { const float* W[8]; unsigned short* Th[8]; int K[8]; int N[8]; };

__global__ __launch_bounds__(256) void tsplit8(TransB8 tb) {
    const int z = blockIdx.z;
    const int K = tb.K[z], N = tb.N[z];
    const int k0 = blockIdx.x * 32, n0 = blockIdx.y * 32;
    if (k0 >= K || n0 >= N) return;
    __shared__ float t[32][33];
    const int tx = threadIdx.x & 31, ty = threadIdx.x >> 5;
    const float* W = tb.W[z];
#pragma unroll
    for (int i = 0; i < 32; i += 8)
        t[ty + i][tx] = W[(size_t)(k0 + ty + i) * N + n0 + tx];
    __syncthreads();
#pragma unroll
    for (int i = 0; i < 32; i += 8) {
        const int n = ty + i;
        tb.Th[z][(size_t)(n0 + n) * K + k0 + tx] = bf16_rne(t[tx][n]);
    }
}

// ---------------- batched GEMM: C(bf16) = A @ B(bf16)^T  (R10/R11-verified) ----------------
// Block 128(M) x NF*32(N), 4 waves (2x2), wave tile 64 x NF*16.
// AF32=1: A f32 reg-staged (issue 2 ahead, cvt+ds_write after barrier); AF32=0: A bf16 glds.
// B: glds depth-2, 3 LDS buffers, counted vmcnt (never 0 in main loop).
// LDS [rows][64B]; granule (row,s), src k-group kg = s ^ ((row>>1)&3)  -> 0 bank conflicts.
struct GemmB {
    const void* A[4];
    const unsigned short* Bh[4];
    unsigned short* C[4];
    int K[4];
    int NT[4];
};

template <int NF, int AF32>
__global__ __launch_bounds__(256, 2) void gemm_bf16s(GemmB gb) {
    constexpr int BGR = NF / 2;
    const int nwg = gridDim.x * gridDim.y * gridDim.z;
    int id = (blockIdx.z * gridDim.y + blockIdx.y) * gridDim.x + blockIdx.x;
    const int cpx = nwg >> 3;
    id = (id & 7) * cpx + (id >> 3);
    const int by = id % gridDim.y;
    const int rest = id / gridDim.y;
    const int bx = rest % gridDim.x;
    const int z = rest / gridDim.x;

    const int nt = gb.NT[z];
    if (by >= nt) return;
    const int K = gb.K[z];
    const int N = nt * (NF * 32);
    const float* __restrict__ Af = (const float*)gb.A[z];
    const unsigned short* __restrict__ Ab = (const unsigned short*)gb.A[z];
    const unsigned short* __restrict__ Bh = gb.Bh[z];
    unsigned short* __restrict__ C = gb.C[z];

    __shared__ unsigned short As[3 * 4096];
    __shared__ unsigned short Bs[3 * NF * 1024];
    const int tid = threadIdx.x;
    const int w = tid >> 6, lane = tid & 63;
    const int wm = w >> 1, wn = w & 1;
    const int bm0 = bx * 128, bn0 = by * (NF * 32);

    auto stageB = [&](int buf, int kt) {
        const int k0 = kt << 5;
#pragma unroll
        for (int i = 0; i < BGR; ++i) {
            const int f = (w * BGR + i) * 64 + lane;
            const int row = f >> 2, s = f & 3;
            const int kg = s ^ ((row >> 1) & 3);
            GLDS16(Bh + (size_t)(bn0 + row) * K + k0 + kg * 8,
                   &Bs[buf * (NF * 1024) + (w * BGR + i) * 512]);
        }
    };
    auto stageAglds = [&](int buf, int kt) {
        const int k0 = kt << 5;
#pragma unroll
        for (int i = 0; i < 2; ++i) {
            const int f = (w * 2 + i) * 64 + lane;
            const int row = f >> 2, s = f & 3;
            const int kg = s ^ ((row >> 1) & 3);
            GLDS16(Ab + (size_t)(bm0 + row) * K + k0 + kg * 8,
                   &As[buf * 4096 + (w * 2 + i) * 512]);
        }
    };
    auto issueA = [&](float4 (&ar)[2][2], int kt) {
        const int k0 = kt << 5;
#pragma unroll
        for (int i = 0; i < 2; ++i) {
            const int f = i * 256 + tid;
            const int row = f >> 2, s = f & 3;
            const int kg = s ^ ((row >> 1) & 3);
            const float* src = Af + (size_t)(bm0 + row) * K + k0 + kg * 8;
            ar[i][0] = *reinterpret_cast<const float4*>(src);
            ar[i][1] = *reinterpret_cast<const float4*>(src + 4);
        }
    };
    auto writeA = [&](float4 (&ar)[2][2], int buf) {
#pragma unroll
        for (int i = 0; i < 2; ++i)
            *reinterpret_cast<bf16x8*>(&As[buf * 4096 + (i * 256 + tid) * 8]) =
                pack8(ar[i][0], ar[i][1]);
    };

    f32x4 acc[4][NF];
#pragma unroll
    for (int mf = 0; mf < 4; ++mf)
#pragma unroll
        for (int nf = 0; nf < NF; ++nf) acc[mf][nf] = (f32x4){0.f, 0.f, 0.f, 0.f};

    const int nk = K >> 5;
    float4 aE[2][2], aO[2][2];

    if constexpr (AF32) {
        issueA(aE, 0); stageB(0, 0);
        issueA(aO, 1); stageB(1, 1);
        asm volatile("s_waitcnt vmcnt(12)" ::: "memory");
        writeA(aE, 0);
        asm volatile("s_waitcnt lgkmcnt(0)" ::: "memory");
    } else {
        stageAglds(0, 0); stageB(0, 0);
        stageAglds(1, 1); stageB(1, 1);
    }

    auto body = [&](int t, float4 (&iset)[2][2], float4 (&wset)[2][2]) {
        const int cb = t % 3;
        if (t + 2 < nk) {
            if constexpr (AF32) issueA(iset, t + 2);
            else stageAglds((t + 2) % 3, t + 2);
            stageB((t + 2) % 3, t + 2);
            if constexpr (AF32) asm volatile("s_waitcnt vmcnt(16)" ::: "memory");
            else asm volatile("s_waitcnt vmcnt(8)" ::: "memory");
        } else if (t + 1 < nk) {
            if constexpr (AF32) asm volatile("s_waitcnt vmcnt(8)" ::: "memory");
            else asm volatile("s_waitcnt vmcnt(4)" ::: "memory");
        } else {
            asm volatile("s_waitcnt vmcnt(0)" ::: "memory");
        }
        __builtin_amdgcn_s_barrier();
        __builtin_amdgcn_sched_barrier(0);

        if constexpr (AF32) {
            if (t + 1 < nk) {
                if (t + 2 < nk) asm volatile("s_waitcnt vmcnt(12)" ::: "memory");
                else asm volatile("s_waitcnt vmcnt(4)" ::: "memory");
                writeA(wset, (t + 1) % 3);
            }
        }

        const int kq = lane >> 4;
        bf16x8 a[4], b[NF];
#pragma unroll
        for (int mf = 0; mf < 4; ++mf) {
            const int r = wm * 64 + mf * 16 + (lane & 15);
            a[mf] = *reinterpret_cast<const bf16x8*>(
                &As[cb * 4096 + r * 32 + ((kq ^ ((r >> 1) & 3)) << 3)]);
        }
#pragma unroll
        for (int nf = 0; nf < NF; ++nf) {
            const int r = wn * (NF * 16) + nf * 16 + (lane & 15);
            b[nf] = *reinterpret_cast<const bf16x8*>(
                &Bs[cb * (NF * 1024) + r * 32 + ((kq ^ ((r >> 1) & 3)) << 3)]);
        }
        __builtin_amdgcn_s_setprio(1);
#pragma unroll
        for (int mf = 0; mf < 4; ++mf)
#pragma unroll
            for (int nf = 0; nf < NF; ++nf)
                acc[mf][nf] = __builtin_amdgcn_mfma_f32_16x16x32_bf16(a[mf], b[nf], acc[mf][nf], 0, 0, 0);
        __builtin_amdgcn_s_setprio(0);

        asm volatile("s_waitcnt lgkmcnt(0)" ::: "memory");
        __builtin_amdgcn_s_barrier();
    };

    for (int t = 0; t < nk; t += 2) {
        body(t, aE, aO);
        body(t + 1, aO, aE);
    }

    const int cr = (lane >> 4) * 4, cc = lane & 15;
#pragma unroll
    for (int mf = 0; mf < 4; ++mf)
#pragma unroll
        for (int nf = 0; nf < NF; ++nf)
#pragma unroll
            for (int j = 0; j < 4; ++j)
                C[(size_t)(bm0 + wm * 64 + mf * 16 + cr + j) * N + bn0 + wn * (NF * 16) + nf * 16 + cc] =
                    bf16_rne(acc[mf][nf][j]);
}

// ---------------- batched CSR build (4 graphs), packed (col,val) edges ----------------
struct GraphPtrs {
    const int* r[4];
    const int* c[4];
    const float* v[4];
};

__global__ __launch_bounds__(256) void hist4(GraphPtrs p, int* __restrict__ cnt4) {
    const int g = blockIdx.y;
    const int e = blockIdx.x * 256 + threadIdx.x;
    atomicAdd(&cnt4[g * N_NODES + p.r[g][e]], 1);
}

__global__ __launch_bounds__(256) void scan4(const int* __restrict__ cnt4,
                                             int* __restrict__ rs4,
                                             int* __restrict__ cur4) {
    const int g = blockIdx.x;
    const int* cnt = cnt4 + g * N_NODES;
    int* row_start = rs4 + (size_t)g * (N_NODES + 1);
    int* cursor = cur4 + g * N_NODES;
    __shared__ int ssum[256];
    const int t = threadIdx.x;
    int local[32];
    int s = 0;
#pragma unroll
    for (int j = 0; j < 32; ++j) { local[j] = cnt[t * 32 + j]; s += local[j]; }
    ssum[t] = s;
    __syncthreads();
    for (int off = 1; off < 256; off <<= 1) {
        const int v = ssum[t];
        const int add = (t >= off) ? ssum[t - off] : 0;
        __syncthreads();
        ssum[t] = v + add;
        __syncthreads();
    }
    int run = (t == 0) ? 0 : ssum[t - 1];
#pragma unroll
    for (int j = 0; j < 32; ++j) {
        row_start[t * 32 + j] = run;
        cursor[t * 32 + j] = run;
        run += local[j];
    }
    if (t == 255) row_start[N_NODES] = run;
}

__global__ __launch_bounds__(256) void scatter4(GraphPtrs p, int* __restrict__ cur4,
                                                unsigned long long* __restrict__ pe4) {
    const int g = blockIdx.y;
    const int e = blockIdx.x * 256 + threadIdx.x;
    const int r = p.r[g][e];
    const int pos = atomicAdd(&cur4[g * N_NODES + r], 1);
    pe4[(size_t)g * N_EDGES + pos] =
        (unsigned long long)(unsigned)p.c[g][e] |
        ((unsigned long long)__float_as_uint(p.v[g][e]) << 32);
}

// ---------------- gather SpMM layer 1: XCD-partitioned, all 4 branches ----------------
struct SpmmB {
    const int* rs[4];
    const unsigned long long* pe[4];
    const unsigned short* Y[4];
    const float* bi[4];
    unsigned short* H[4];
    int nc[4];
};

__global__ __launch_bounds__(256) void spmm_h1x(SpmmB sb) {
    const int id = blockIdx.x;
    const int xcd = id & 7;
    const int z = xcd >> 1;
    const int rb = ((id >> 3) << 1) + (id & 1);
    const int row = rb * 4 + (threadIdx.x >> 6);
    const int lane = threadIdx.x & 63;
    const int nc = sb.nc[z];
    const int* rs = sb.rs[z];
    const int s = rs[row], e1 = rs[row + 1];
    const unsigned long long* pe = sb.pe[z];
    const unsigned short* Y = sb.Y[z];
    const float* bi = sb.bi[z];

    if (nc == 512) {
        const int base = lane * 8;
        float acc[8];
#pragma unroll
        for (int j = 0; j < 8; ++j) acc[j] = 0.f;
        for (int e = s; e < e1; ++e) {
            const unsigned long long ev = pe[e];
            const float v = __uint_as_float((unsigned)(ev >> 32));
            const bf16x8 raw = *reinterpret_cast<const bf16x8*>(
                Y + (size_t)(unsigned)ev * 512 + base);
#pragma unroll
            for (int j = 0; j < 8; ++j)
                acc[j] = fmaf(v, bf2f((unsigned short)raw[j]), acc[j]);
        }
        bf16x8 vh;
#pragma unroll
        for (int j = 0; j < 8; ++j) vh[j] = (short)bf16_rne(lrelu(acc[j] + bi[base + j]));
        *reinterpret_cast<bf16x8*>(sb.H[z] + (size_t)row * 512 + base) = vh;
    } else {
        const int base = lane * 4;
        float acc[4];
#pragma unroll
        for (int j = 0; j < 4; ++j) acc[j] = 0.f;
        for (int e = s; e < e1; ++e) {
            const unsigned long long ev = pe[e];
            const float v = __uint_as_float((unsigned)(ev >> 32));
            const ushort4 raw = *reinterpret_cast<const ushort4*>(
                Y + (size_t)(unsigned)ev * 256 + base);
            acc[0] = fmaf(v, bf2f(raw.x), acc[0]);
            acc[1] = fmaf(v, bf2f(raw.y), acc[1]);
            acc[2] = fmaf(v, bf2f(raw.z), acc[2]);
            acc[3] = fmaf(v, bf2f(raw.w), acc[3]);
        }
        ushort4 vh;
        vh.x = bf16_rne(lrelu(acc[0] + bi[base + 0]));
        vh.y = bf16_rne(lrelu(acc[1] + bi[base + 1]));
        vh.z = bf16_rne(lrelu(acc[2] + bi[base + 2]));
        vh.w = bf16_rne(lrelu(acc[3] + bi[base + 3]));
        *reinterpret_cast<ushort4*>(sb.H[z] + (size_t)row * 256 + base) = vh;
    }
}

// tier-2 single-branch layer-1 spmm
template <int NC>
__global__ __launch_bounds__(256) void spmm_h1(const int* __restrict__ rs,
                                               const unsigned long long* __restrict__ pe,
                                               const unsigned short* __restrict__ Y,
                                               const float* __restrict__ bi,
                                               unsigned short* __restrict__ Hd) {
    constexpr int PL = NC / 64;
    const int row = (blockIdx.x * 256 + threadIdx.x) >> 6;
    const int lane = threadIdx.x & 63;
    const int s = rs[row], e1 = rs[row + 1];
    const int base = lane * PL;
    float acc[PL];
#pragma unroll
    for (int j = 0; j < PL; ++j) acc[j] = 0.f;
    for (int e = s; e < e1; ++e) {
        const unsigned long long ev = pe[e];
        const float v = __uint_as_float((unsigned)(ev >> 32));
        const unsigned short* y = Y + (size_t)(unsigned)ev * NC + base;
        if constexpr (PL == 8) {
            const bf16x8 raw = *reinterpret_cast<const bf16x8*>(y);
#pragma unroll
            for (int j = 0; j < 8; ++j)
                acc[j] = fmaf(v, bf2f((unsigned short)raw[j]), acc[j]);
        } else {
            const ushort4 raw = *reinterpret_cast<const ushort4*>(y);
            acc[0] = fmaf(v, bf2f(raw.x), acc[0]);
            acc[1] = fmaf(v, bf2f(raw.y), acc[1]);
            acc[2] = fmaf(v, bf2f(raw.z), acc[2]);
            acc[3] = fmaf(v, bf2f(raw.w), acc[3]);
        }
    }
    unsigned short* H = Hd + (size_t)row * NC + base;
    if constexpr (PL == 8) {
        bf16x8 vh;
#pragma unroll
        for (int j = 0; j < 8; ++j) vh[j] = (short)bf16_rne(lrelu(acc[j] + bi[base + j]));
        *reinterpret_cast<bf16x8*>(H) = vh;
    } else {
        ushort4 vh;
        vh.x = bf16_rne(lrelu(acc[0] + bi[base + 0]));
        vh.y = bf16_rne(lrelu(acc[1] + bi[base + 1]));
        vh.z = bf16_rne(lrelu(acc[2] + bi[base + 2]));
        vh.w = bf16_rne(lrelu(acc[3] + bi[base + 3]));
        *reinterpret_cast<ushort4*>(H) = vh;
    }
}

// ---------------- fused output: out[row] = 0.25 * sum_b lrelu(spmm_b(Y2_b)[row] + b2_b) ----------------
struct Out4 { const float* b2[4]; };

__global__ __launch_bounds__(256) void spmm_out4(const int* __restrict__ rs4,
                                                 const unsigned long long* __restrict__ pe4,
                                                 const unsigned short* __restrict__ Y2all,
                                                 Out4 ob, float* __restrict__ out) {
    const int row = (blockIdx.x * 256 + threadIdx.x) >> 6;
    const int lane = threadIdx.x & 63;
    const int base = lane * 2;
    float r0 = 0.f, r1 = 0.f;
#pragma unroll
    for (int b = 0; b < 4; ++b) {
        const int* rs = rs4 + (size_t)b * (N_NODES + 1);
        const int s = rs[row], e1 = rs[row + 1];
        const unsigned long long* pe = pe4 + (size_t)b * N_EDGES;
        const unsigned short* Y = Y2all + (size_t)b * N_NODES * 128;
        float a0 = 0.f, a1 = 0.f;
        for (int e = s; e < e1; ++e) {
            const unsigned long long ev = pe[e];
            const float v = __uint_as_float((unsigned)(ev >> 32));
            const unsigned u = *reinterpret_cast<const unsigned*>(
                Y + (size_t)(unsigned)ev * 128 + base);
            a0 = fmaf(v, __uint_as_float(u << 16), a0);
            a1 = fmaf(v, __uint_as_float(u & 0xFFFF0000u), a1);
        }
        const float* bi = ob.b2[b];
        r0 += lrelu(a0 + bi[base]);
        r1 += lrelu(a1 + bi[base + 1]);
    }
    *reinterpret_cast<float2*>(out + (size_t)row * 128 + base) =
        make_float2(0.25f * r0, 0.25f * r1);
}

// tier-2 single-branch output accumulate
__global__ __launch_bounds__(256) void spmm_out1(const int* __restrict__ rs,
                                                 const unsigned long long* __restrict__ pe,
                                                 const unsigned short* __restrict__ Y,
                                                 const float* __restrict__ bias,
                                                 float* __restrict__ out, int first) {
    const int row = (blockIdx.x * 256 + threadIdx.x) >> 6;
    const int lane = threadIdx.x & 63;
    const int base = lane * 2;
    const int s = rs[row], e1 = rs[row + 1];
    float a0 = 0.f, a1 = 0.f;
    for (int e = s; e < e1; ++e) {
        const unsigned long long ev = pe[e];
        const float v = __uint_as_float((unsigned)(ev >> 32));
        const unsigned u = *reinterpret_cast<const unsigned*>(
            Y + (size_t)(unsigned)ev * 128 + base);
        a0 = fmaf(v, __uint_as_float(u << 16), a0);
        a1 = fmaf(v, __uint_as_float(u & 0xFFFF0000u), a1);
    }
    float r0 = 0.25f * lrelu(a0 + bias[base]);
    float r1 = 0.25f * lrelu(a1 + bias[base + 1]);
    float* o = out + (size_t)row * 128 + base;
    if (!first) {
        const float2 p = *reinterpret_cast<const float2*>(o);
        r0 += p.x;
        r1 += p.y;
    }
    *reinterpret_cast<float2*>(o) = make_float2(r0, r1);
}

extern "C" void kernel_launch(void* const* d_in, const int* in_sizes, int n_in,
                              void* d_out, int out_size, void* d_ws, size_t ws_size,
                              hipStream_t stream) {
    const float* X[4] = {(const float*)d_in[0], (const float*)d_in[1],
                         (const float*)d_in[2], (const float*)d_in[3]};
    GraphPtrs gp;
    for (int b = 0; b < 4; ++b) {
        gp.r[b] = (const int*)d_in[4 + 3 * b];
        gp.c[b] = (const int*)d_in[5 + 3 * b];
        gp.v[b] = (const float*)d_in[6 + 3 * b];
    }
    const float *w1[4], *b1[4], *w2[4], *b2[4];
    for (int b = 0; b < 4; ++b) {
        w1[b] = (const float*)d_in[16 + 4 * b + 0];
        b1[b] = (const float*)d_in[16 + 4 * b + 1];
        w2[b] = (const float*)d_in[16 + 4 * b + 2];
        b2[b] = (const float*)d_in[16 + 4 * b + 3];
    }
    const int din[4] = {4096, 4096, 4096, 1024};
    const int dh[4] = {512, 512, 512, 256};
    float* out = (float*)d_out;

    char* wsc = (char*)d_ws;
    size_t off = 0;
    auto carve = [&](size_t bytes) {
        void* p = wsc + off;
        off += (bytes + 255) & ~(size_t)255;
        return p;
    };
    int* cnt4 = (int*)carve((size_t)4 * N_NODES * 4);
    int* rs4 = (int*)carve((size_t)4 * (N_NODES + 1) * 4);
    int* cur4 = (int*)carve((size_t)4 * N_NODES * 4);
    unsigned long long* pe4 = (unsigned long long*)carve((size_t)4 * N_EDGES * 8);

    size_t tier1_base = off;
    unsigned short *W1h[4], *W2h[4], *Y1[4], *H1[4];
    for (int b = 0; b < 4; ++b) W1h[b] = (unsigned short*)carve((size_t)dh[b] * din[b] * 2);
    for (int b = 0; b < 4; ++b) W2h[b] = (unsigned short*)carve((size_t)128 * dh[b] * 2);
    for (int b = 0; b < 4; ++b) Y1[b] = (unsigned short*)carve((size_t)N_NODES * dh[b] * 2);
    for (int b = 0; b < 4; ++b) H1[b] = (unsigned short*)carve((size_t)N_NODES * dh[b] * 2);
    unsigned short* Y2all = (unsigned short*)carve((size_t)4 * N_NODES * 128 * 2);
    const bool tier1 = (off <= ws_size);
    unsigned short* Y2s[4];
    if (tier1) {
        for (int b = 0; b < 4; ++b) Y2s[b] = Y2all + (size_t)b * N_NODES * 128;
    } else {
        off = tier1_base;
        unsigned short* w1h = (unsigned short*)carve((size_t)512 * 4096 * 2);
        unsigned short* w2h = (unsigned short*)carve((size_t)128 * 512 * 2);
        unsigned short* y1 = (unsigned short*)carve((size_t)N_NODES * 512 * 2);
        unsigned short* h1 = (unsigned short*)carve((size_t)N_NODES * 512 * 2);
        unsigned short* y2 = (unsigned short*)carve((size_t)N_NODES * 128 * 2);
        for (int b = 0; b < 4; ++b) {
            W1h[b] = w1h; W2h[b] = w2h;
            Y1[b] = y1; H1[b] = h1; Y2s[b] = y2;
        }
    }

    // ---- batched CSR build ----
    hipMemsetAsync(cnt4, 0, (size_t)4 * N_NODES * sizeof(int), stream);
    {
        dim3 g(N_EDGES / 256, 4);
        hist4<<<g, 256, 0, stream>>>(gp, cnt4);
        scan4<<<4, 256, 0, stream>>>(cnt4, rs4, cur4);
        scatter4<<<g, 256, 0, stream>>>(gp, cur4, pe4);
    }

    if (tier1) {
        // single batched transpose for W1 (slots 0-3) and W2 (slots 4-7)
        TransB8 tt;
        for (int b = 0; b < 4; ++b) {
            tt.W[b] = w1[b]; tt.Th[b] = W1h[b]; tt.K[b] = din[b]; tt.N[b] = dh[b];
            tt.W[4 + b] = w2[b]; tt.Th[4 + b] = W2h[b]; tt.K[4 + b] = dh[b]; tt.N[4 + b] = 128;
        }
        tsplit8<<<dim3(128, 16, 8), 256, 0, stream>>>(tt);

        GemmB g1;
        for (int b = 0; b < 4; ++b) {
            g1.A[b] = X[b]; g1.Bh[b] = W1h[b];
            g1.C[b] = Y1[b]; g1.K[b] = din[b]; g1.NT[b] = dh[b] / 256;
        }
        gemm_bf16s<8, 1><<<dim3(64, 2, 4), 256, 0, stream>>>(g1);

        SpmmB s1;
        for (int b = 0; b < 4; ++b) {
            s1.rs[b] = rs4 + (size_t)b * (N_NODES + 1);
            s1.pe[b] = pe4 + (size_t)b * N_EDGES;
            s1.Y[b] = Y1[b]; s1.bi[b] = b1[b]; s1.H[b] = H1[b];
            s1.nc[b] = dh[b];
        }
        spmm_h1x<<<8192, 256, 0, stream>>>(s1);

        GemmB g2;
        for (int b = 0; b < 4; ++b) {
            g2.A[b] = H1[b]; g2.Bh[b] = W2h[b];
            g2.C[b] = Y2s[b]; g2.K[b] = dh[b]; g2.NT[b] = 1;
        }
        gemm_bf16s<4, 0><<<dim3(64, 1, 4), 256, 0, stream>>>(g2);

        Out4 ob;
        for (int b = 0; b < 4; ++b) ob.b2[b] = b2[b];
        spmm_out4<<<N_NODES / 4, 256, 0, stream>>>(rs4, pe4, Y2all, ob, out);
    } else {
        for (int b = 0; b < 4; ++b) {
            TransB8 tt;
            tt.W[0] = w1[b]; tt.Th[0] = W1h[b]; tt.K[0] = din[b]; tt.N[0] = dh[b];
            tsplit8<<<dim3(din[b] / 32, dh[b] / 32, 1), 256, 0, stream>>>(tt);
            GemmB g1;
            g1.A[0] = X[b]; g1.Bh[0] = W1h[b];
            g1.C[0] = Y1[b]; g1.K[0] = din[b]; g1.NT[0] = dh[b] / 256;
            gemm_bf16s<8, 1><<<dim3(64, dh[b] / 256 ? dh[b] / 256 : 1, 1), 256, 0, stream>>>(g1);
            if (dh[b] == 512)
                spmm_h1<512><<<N_NODES / 4, 256, 0, stream>>>(
                    rs4 + (size_t)b * (N_NODES + 1), pe4 + (size_t)b * N_EDGES,
                    Y1[b], b1[b], H1[b]);
            else
                spmm_h1<256><<<N_NODES / 4, 256, 0, stream>>>(
                    rs4 + (size_t)b * (N_NODES + 1), pe4 + (size_t)b * N_EDGES,
                    Y1[b], b1[b], H1[b]);
            TransB8 t2;
            t2.W[0] = w2[b]; t2.Th[0] = W2h[b]; t2.K[0] = dh[b]; t2.N[0] = 128;
            tsplit8<<<dim3(dh[b] / 32, 4, 1), 256, 0, stream>>>(t2);
            GemmB g2;
            g2.A[0] = H1[b]; g2.Bh[0] = W2h[b];
            g2.C[0] = Y2s[b]; g2.K[0] = dh[b]; g2.NT[0] = 1;
            gemm_bf16s<4, 0><<<dim3(64, 1, 1), 256, 0, stream>>>(g2);
            spmm_out1<<<N_NODES / 4, 256, 0, stream>>>(
                rs4 + (size_t)b * (N_NODES + 1), pe4 + (size_t)b * N_EDGES,
                Y2s[b], b2[b], out, b == 0);
        }
    }
}

// Round 14
// 527.499 us; speedup vs baseline: 1.5900x; 1.0121x over previous
//
#include <hip/hip_runtime.h>

#define N_NODES 8192
#define N_EDGES 262144
#define SLOPE 0.25f

typedef __attribute__((ext_vector_type(8))) short bf16x8;
typedef __attribute__((ext_vector_type(4))) float f32x4;

__device__ __forceinline__ float lrelu(float x) { return x >= 0.f ? x : SLOPE * x; }

__device__ __forceinline__ unsigned short bf16_rne(float x) {
    unsigned u = __float_as_uint(x);
    return (unsigned short)((u + 0x7FFFu + ((u >> 16) & 1u)) >> 16);
}
__device__ __forceinline__ float bf2f(unsigned short h) {
    return __uint_as_float(((unsigned)h) << 16);
}
// truncation pack: [lo16 = a_hi16 | hi16 = b_hi16] via one v_perm_b32
__device__ __forceinline__ unsigned packtr(float a, float b) {
    return __builtin_amdgcn_perm(__float_as_uint(b), __float_as_uint(a), 0x07060302u);
}
__device__ __forceinline__ bf16x8 pack8t(const float4& a, const float4& b) {
    union { unsigned u[4]; bf16x8 v; } r;
    r.u[0] = packtr(a.x, a.y);
    r.u[1] = packtr(a.z, a.w);
    r.u[2] = packtr(b.x, b.y);
    r.u[3] = packtr(b.z, b.w);
    return r.v;
}

#define GLDS16(g, l)                                                              \
    __builtin_amdgcn_global_load_lds((const __attribute__((address_space(1))) void*)(g), \
                                     (__attribute__((address_space(3))) void*)(l), 16, 0, 0)

// ---------------- batched W [K,N] f32 -> WT bf16 [N,K] (transpose + round), 8 slots ----------------
struct TransB8 { const float* W[8]; unsigned short* Th[8]; int K[8]; int N[8]; };

__global__ __launch_bounds__(256) void tsplit8(TransB8 tb) {
    const int z = blockIdx.z;
    const int K = tb.K[z], N = tb.N[z];
    const int k0 = blockIdx.x * 32, n0 = blockIdx.y * 32;
    if (k0 >= K || n0 >= N) return;
    __shared__ float t[32][33];
    const int tx = threadIdx.x & 31, ty = threadIdx.x >> 5;
    const float* W = tb.W[z];
#pragma unroll
    for (int i = 0; i < 32; i += 8)
        t[ty + i][tx] = W[(size_t)(k0 + ty + i) * N + n0 + tx];
    __syncthreads();
#pragma unroll
    for (int i = 0; i < 32; i += 8) {
        const int n = ty + i;
        tb.Th[z][(size_t)(n0 + n) * K + k0 + tx] = bf16_rne(t[tx][n]);
    }
}

// ---------------- batched GEMM: C(bf16) = A @ B(bf16)^T ----------------
// Block 128(M) x NF*32(N), 4 waves (2x2), wave tile 64 x NF*16.
// AF32=1: A f32 reg-staged (issue 2 ahead, v_perm trunc-pack + ds_write after reads).
// AF32=0: A bf16 glds. B: glds depth-2, 3 LDS buffers, counted vmcnt.
// LDS [rows][64B]; granule (row,s), src k-group kg = s ^ ((row>>1)&3) -> 0 bank conflicts.
struct GemmB {
    const void* A[4];
    const unsigned short* Bh[4];
    unsigned short* C[4];
    int K[4];
    int NT[4];
};

template <int NF, int AF32>
__global__ __launch_bounds__(256, 2) void gemm_bf16s(GemmB gb) {
    constexpr int BGR = NF / 2;
    const int nwg = gridDim.x * gridDim.y * gridDim.z;
    int id = (blockIdx.z * gridDim.y + blockIdx.y) * gridDim.x + blockIdx.x;
    const int cpx = nwg >> 3;
    id = (id & 7) * cpx + (id >> 3);
    const int by = id % gridDim.y;
    const int rest = id / gridDim.y;
    const int bx = rest % gridDim.x;
    const int z = rest / gridDim.x;

    const int nt = gb.NT[z];
    if (by >= nt) return;
    const int K = gb.K[z];
    const int N = nt * (NF * 32);
    const float* __restrict__ Af = (const float*)gb.A[z];
    const unsigned short* __restrict__ Ab = (const unsigned short*)gb.A[z];
    const unsigned short* __restrict__ Bh = gb.Bh[z];
    unsigned short* __restrict__ C = gb.C[z];

    __shared__ unsigned short As[3 * 4096];
    __shared__ unsigned short Bs[3 * NF * 1024];
    const int tid = threadIdx.x;
    const int w = tid >> 6, lane = tid & 63;
    const int wm = w >> 1, wn = w & 1;
    const int bm0 = bx * 128, bn0 = by * (NF * 32);

    auto stageB = [&](int buf, int kt) {
        const int k0 = kt << 5;
#pragma unroll
        for (int i = 0; i < BGR; ++i) {
            const int f = (w * BGR + i) * 64 + lane;
            const int row = f >> 2, s = f & 3;
            const int kg = s ^ ((row >> 1) & 3);
            GLDS16(Bh + (size_t)(bn0 + row) * K + k0 + kg * 8,
                   &Bs[buf * (NF * 1024) + (w * BGR + i) * 512]);
        }
    };
    auto stageAglds = [&](int buf, int kt) {
        const int k0 = kt << 5;
#pragma unroll
        for (int i = 0; i < 2; ++i) {
            const int f = (w * 2 + i) * 64 + lane;
            const int row = f >> 2, s = f & 3;
            const int kg = s ^ ((row >> 1) & 3);
            GLDS16(Ab + (size_t)(bm0 + row) * K + k0 + kg * 8,
                   &As[buf * 4096 + (w * 2 + i) * 512]);
        }
    };
    auto issueA = [&](float4 (&ar)[2][2], int kt) {
        const int k0 = kt << 5;
#pragma unroll
        for (int i = 0; i < 2; ++i) {
            const int f = i * 256 + tid;
            const int row = f >> 2, s = f & 3;
            const int kg = s ^ ((row >> 1) & 3);
            const float* src = Af + (size_t)(bm0 + row) * K + k0 + kg * 8;
            ar[i][0] = *reinterpret_cast<const float4*>(src);
            ar[i][1] = *reinterpret_cast<const float4*>(src + 4);
        }
    };
    auto writeA = [&](float4 (&ar)[2][2], int buf) {
#pragma unroll
        for (int i = 0; i < 2; ++i)
            *reinterpret_cast<bf16x8*>(&As[buf * 4096 + (i * 256 + tid) * 8]) =
                pack8t(ar[i][0], ar[i][1]);
    };

    f32x4 acc[4][NF];
#pragma unroll
    for (int mf = 0; mf < 4; ++mf)
#pragma unroll
        for (int nf = 0; nf < NF; ++nf) acc[mf][nf] = (f32x4){0.f, 0.f, 0.f, 0.f};

    const int nk = K >> 5;
    float4 aE[2][2], aO[2][2];

    if constexpr (AF32) {
        issueA(aE, 0); stageB(0, 0);
        issueA(aO, 1); stageB(1, 1);
        asm volatile("s_waitcnt vmcnt(12)" ::: "memory");
        writeA(aE, 0);
        asm volatile("s_waitcnt lgkmcnt(0)" ::: "memory");
    } else {
        stageAglds(0, 0); stageB(0, 0);
        stageAglds(1, 1); stageB(1, 1);
    }

    auto body = [&](int t, float4 (&iset)[2][2], float4 (&wset)[2][2]) {
        const int cb = t % 3;
        if (t + 2 < nk) {
            if constexpr (AF32) issueA(iset, t + 2);
            else stageAglds((t + 2) % 3, t + 2);
            stageB((t + 2) % 3, t + 2);
            if constexpr (AF32) asm volatile("s_waitcnt vmcnt(16)" ::: "memory");
            else asm volatile("s_waitcnt vmcnt(8)" ::: "memory");
        } else if (t + 1 < nk) {
            if constexpr (AF32) asm volatile("s_waitcnt vmcnt(8)" ::: "memory");
            else asm volatile("s_waitcnt vmcnt(4)" ::: "memory");
        } else {
            asm volatile("s_waitcnt vmcnt(0)" ::: "memory");
        }
        __builtin_amdgcn_s_barrier();
        __builtin_amdgcn_sched_barrier(0);

        // fragment reads FIRST (buffer cb; independent of writeA's target buffer)
        const int kq = lane >> 4;
        bf16x8 a[4], b[NF];
#pragma unroll
        for (int mf = 0; mf < 4; ++mf) {
            const int r = wm * 64 + mf * 16 + (lane & 15);
            a[mf] = *reinterpret_cast<const bf16x8*>(
                &As[cb * 4096 + r * 32 + ((kq ^ ((r >> 1) & 3)) << 3)]);
        }
#pragma unroll
        for (int nf = 0; nf < NF; ++nf) {
            const int r = wn * (NF * 16) + nf * 16 + (lane & 15);
            b[nf] = *reinterpret_cast<const bf16x8*>(
                &Bs[cb * (NF * 1024) + r * 32 + ((kq ^ ((r >> 1) & 3)) << 3)]);
        }

        // A-stage write AFTER the reads: its ds_writes drain under the MFMA block
        if constexpr (AF32) {
            if (t + 1 < nk) {
                if (t + 2 < nk) asm volatile("s_waitcnt vmcnt(12)" ::: "memory");
                else asm volatile("s_waitcnt vmcnt(4)" ::: "memory");
                writeA(wset, (t + 1) % 3);
            }
        }

        __builtin_amdgcn_s_setprio(1);
#pragma unroll
        for (int mf = 0; mf < 4; ++mf)
#pragma unroll
            for (int nf = 0; nf < NF; ++nf)
                acc[mf][nf] = __builtin_amdgcn_mfma_f32_16x16x32_bf16(a[mf], b[nf], acc[mf][nf], 0, 0, 0);
        __builtin_amdgcn_s_setprio(0);

        asm volatile("s_waitcnt lgkmcnt(0)" ::: "memory");
        __builtin_amdgcn_s_barrier();
    };

    for (int t = 0; t < nk; t += 2) {
        body(t, aE, aO);
        body(t + 1, aO, aE);
    }

    const int cr = (lane >> 4) * 4, cc = lane & 15;
#pragma unroll
    for (int mf = 0; mf < 4; ++mf)
#pragma unroll
        for (int nf = 0; nf < NF; ++nf)
#pragma unroll
            for (int j = 0; j < 4; ++j)
                C[(size_t)(bm0 + wm * 64 + mf * 16 + cr + j) * N + bn0 + wn * (NF * 16) + nf * 16 + cc] =
                    bf16_rne(acc[mf][nf][j]);
}

// ---------------- batched CSR build (4 graphs), packed (col,val) edges ----------------
struct GraphPtrs {
    const int* r[4];
    const int* c[4];
    const float* v[4];
};

__global__ __launch_bounds__(256) void hist4(GraphPtrs p, int* __restrict__ cnt4) {
    const int g = blockIdx.y;
    const int e = blockIdx.x * 256 + threadIdx.x;
    atomicAdd(&cnt4[g * N_NODES + p.r[g][e]], 1);
}

__global__ __launch_bounds__(256) void scan4(const int* __restrict__ cnt4,
                                             int* __restrict__ rs4,
                                             int* __restrict__ cur4) {
    const int g = blockIdx.x;
    const int* cnt = cnt4 + g * N_NODES;
    int* row_start = rs4 + (size_t)g * (N_NODES + 1);
    int* cursor = cur4 + g * N_NODES;
    __shared__ int ssum[256];
    const int t = threadIdx.x;
    int local[32];
    int s = 0;
#pragma unroll
    for (int j = 0; j < 32; ++j) { local[j] = cnt[t * 32 + j]; s += local[j]; }
    ssum[t] = s;
    __syncthreads();
    for (int off = 1; off < 256; off <<= 1) {
        const int v = ssum[t];
        const int add = (t >= off) ? ssum[t - off] : 0;
        __syncthreads();
        ssum[t] = v + add;
        __syncthreads();
    }
    int run = (t == 0) ? 0 : ssum[t - 1];
#pragma unroll
    for (int j = 0; j < 32; ++j) {
        row_start[t * 32 + j] = run;
        cursor[t * 32 + j] = run;
        run += local[j];
    }
    if (t == 255) row_start[N_NODES] = run;
}

__global__ __launch_bounds__(256) void scatter4(GraphPtrs p, int* __restrict__ cur4,
                                                unsigned long long* __restrict__ pe4) {
    const int g = blockIdx.y;
    const int e = blockIdx.x * 256 + threadIdx.x;
    const int r = p.r[g][e];
    const int pos = atomicAdd(&cur4[g * N_NODES + r], 1);
    pe4[(size_t)g * N_EDGES + pos] =
        (unsigned long long)(unsigned)p.c[g][e] |
        ((unsigned long long)__float_as_uint(p.v[g][e]) << 32);
}

// ---------------- gather SpMM layer 1: XCD-partitioned, all 4 branches ----------------
struct SpmmB {
    const int* rs[4];
    const unsigned long long* pe[4];
    const unsigned short* Y[4];
    const float* bi[4];
    unsigned short* H[4];
    int nc[4];
};

__global__ __launch_bounds__(256) void spmm_h1x(SpmmB sb) {
    const int id = blockIdx.x;
    const int xcd = id & 7;
    const int z = xcd >> 1;
    const int rb = ((id >> 3) << 1) + (id & 1);
    const int row = rb * 4 + (threadIdx.x >> 6);
    const int lane = threadIdx.x & 63;
    const int nc = sb.nc[z];
    const int* rs = sb.rs[z];
    const int s = rs[row], e1 = rs[row + 1];
    const unsigned long long* pe = sb.pe[z];
    const unsigned short* Y = sb.Y[z];
    const float* bi = sb.bi[z];

    if (nc == 512) {
        const int base = lane * 8;
        float acc[8];
#pragma unroll
        for (int j = 0; j < 8; ++j) acc[j] = 0.f;
        for (int e = s; e < e1; ++e) {
            const unsigned long long ev = pe[e];
            const float v = __uint_as_float((unsigned)(ev >> 32));
            const bf16x8 raw = *reinterpret_cast<const bf16x8*>(
                Y + (size_t)(unsigned)ev * 512 + base);
#pragma unroll
            for (int j = 0; j < 8; ++j)
                acc[j] = fmaf(v, bf2f((unsigned short)raw[j]), acc[j]);
        }
        bf16x8 vh;
#pragma unroll
        for (int j = 0; j < 8; ++j) vh[j] = (short)bf16_rne(lrelu(acc[j] + bi[base + j]));
        *reinterpret_cast<bf16x8*>(sb.H[z] + (size_t)row * 512 + base) = vh;
    } else {
        const int base = lane * 4;
        float acc[4];
#pragma unroll
        for (int j = 0; j < 4; ++j) acc[j] = 0.f;
        for (int e = s; e < e1; ++e) {
            const unsigned long long ev = pe[e];
            const float v = __uint_as_float((unsigned)(ev >> 32));
            const ushort4 raw = *reinterpret_cast<const ushort4*>(
                Y + (size_t)(unsigned)ev * 256 + base);
            acc[0] = fmaf(v, bf2f(raw.x), acc[0]);
            acc[1] = fmaf(v, bf2f(raw.y), acc[1]);
            acc[2] = fmaf(v, bf2f(raw.z), acc[2]);
            acc[3] = fmaf(v, bf2f(raw.w), acc[3]);
        }
        ushort4 vh;
        vh.x = bf16_rne(lrelu(acc[0] + bi[base + 0]));
        vh.y = bf16_rne(lrelu(acc[1] + bi[base + 1]));
        vh.z = bf16_rne(lrelu(acc[2] + bi[base + 2]));
        vh.w = bf16_rne(lrelu(acc[3] + bi[base + 3]));
        *reinterpret_cast<ushort4*>(sb.H[z] + (size_t)row * 256 + base) = vh;
    }
}

// tier-2 single-branch layer-1 spmm
template <int NC>
__global__ __launch_bounds__(256) void spmm_h1(const int* __restrict__ rs,
                                               const unsigned long long* __restrict__ pe,
                                               const unsigned short* __restrict__ Y,
                                               const float* __restrict__ bi,
                                               unsigned short* __restrict__ Hd) {
    constexpr int PL = NC / 64;
    const int row = (blockIdx.x * 256 + threadIdx.x) >> 6;
    const int lane = threadIdx.x & 63;
    const int s = rs[row], e1 = rs[row + 1];
    const int base = lane * PL;
    float acc[PL];
#pragma unroll
    for (int j = 0; j < PL; ++j) acc[j] = 0.f;
    for (int e = s; e < e1; ++e) {
        const unsigned long long ev = pe[e];
        const float v = __uint_as_float((unsigned)(ev >> 32));
        const unsigned short* y = Y + (size_t)(unsigned)ev * NC + base;
        if constexpr (PL == 8) {
            const bf16x8 raw = *reinterpret_cast<const bf16x8*>(y);
#pragma unroll
            for (int j = 0; j < 8; ++j)
                acc[j] = fmaf(v, bf2f((unsigned short)raw[j]), acc[j]);
        } else {
            const ushort4 raw = *reinterpret_cast<const ushort4*>(y);
            acc[0] = fmaf(v, bf2f(raw.x), acc[0]);
            acc[1] = fmaf(v, bf2f(raw.y), acc[1]);
            acc[2] = fmaf(v, bf2f(raw.z), acc[2]);
            acc[3] = fmaf(v, bf2f(raw.w), acc[3]);
        }
    }
    unsigned short* H = Hd + (size_t)row * NC + base;
    if constexpr (PL == 8) {
        bf16x8 vh;
#pragma unroll
        for (int j = 0; j < 8; ++j) vh[j] = (short)bf16_rne(lrelu(acc[j] + bi[base + j]));
        *reinterpret_cast<bf16x8*>(H) = vh;
    } else {
        ushort4 vh;
        vh.x = bf16_rne(lrelu(acc[0] + bi[base + 0]));
        vh.y = bf16_rne(lrelu(acc[1] + bi[base + 1]));
        vh.z = bf16_rne(lrelu(acc[2] + bi[base + 2]));
        vh.w = bf16_rne(lrelu(acc[3] + bi[base + 3]));
        *reinterpret_cast<ushort4*>(H) = vh;
    }
}

// ---------------- fused output: out[row] = 0.25 * sum_b lrelu(spmm_b(Y2_b)[row] + b2_b) ----------------
struct Out4 { const float* b2[4]; };

__global__ __launch_bounds__(256) void spmm_out4(const int* __restrict__ rs4,
                                                 const unsigned long long* __restrict__ pe4,
                                                 const unsigned short* __restrict__ Y2all,
                                                 Out4 ob, float* __restrict__ out) {
    const int row = (blockIdx.x * 256 + threadIdx.x) >> 6;
    const int lane = threadIdx.x & 63;
    const int base = lane * 2;
    float r0 = 0.f, r1 = 0.f;
#pragma unroll
    for (int b = 0; b < 4; ++b) {
        const int* rs = rs4 + (size_t)b * (N_NODES + 1);
        const int s = rs[row], e1 = rs[row + 1];
        const unsigned long long* pe = pe4 + (size_t)b * N_EDGES;
        const unsigned short* Y = Y2all + (size_t)b * N_NODES * 128;
        float a0 = 0.f, a1 = 0.f;
        for (int e = s; e < e1; ++e) {
            const unsigned long long ev = pe[e];
            const float v = __uint_as_float((unsigned)(ev >> 32));
            const unsigned u = *reinterpret_cast<const unsigned*>(
                Y + (size_t)(unsigned)ev * 128 + base);
            a0 = fmaf(v, __uint_as_float(u << 16), a0);
            a1 = fmaf(v, __uint_as_float(u & 0xFFFF0000u), a1);
        }
        const float* bi = ob.b2[b];
        r0 += lrelu(a0 + bi[base]);
        r1 += lrelu(a1 + bi[base + 1]);
    }
    *reinterpret_cast<float2*>(out + (size_t)row * 128 + base) =
        make_float2(0.25f * r0, 0.25f * r1);
}

// tier-2 single-branch output accumulate
__global__ __launch_bounds__(256) void spmm_out1(const int* __restrict__ rs,
                                                 const unsigned long long* __restrict__ pe,
                                                 const unsigned short* __restrict__ Y,
                                                 const float* __restrict__ bias,
                                                 float* __restrict__ out, int first) {
    const int row = (blockIdx.x * 256 + threadIdx.x) >> 6;
    const int lane = threadIdx.x & 63;
    const int base = lane * 2;
    const int s = rs[row], e1 = rs[row + 1];
    float a0 = 0.f, a1 = 0.f;
    for (int e = s; e < e1; ++e) {
        const unsigned long long ev = pe[e];
        const float v = __uint_as_float((unsigned)(ev >> 32));
        const unsigned u = *reinterpret_cast<const unsigned*>(
            Y + (size_t)(unsigned)ev * 128 + base);
        a0 = fmaf(v, __uint_as_float(u << 16), a0);
        a1 = fmaf(v, __uint_as_float(u & 0xFFFF0000u), a1);
    }
    float r0 = 0.25f * lrelu(a0 + bias[base]);
    float r1 = 0.25f * lrelu(a1 + bias[base + 1]);
    float* o = out + (size_t)row * 128 + base;
    if (!first) {
        const float2 p = *reinterpret_cast<const float2*>(o);
        r0 += p.x;
        r1 += p.y;
    }
    *reinterpret_cast<float2*>(o) = make_float2(r0, r1);
}

extern "C" void kernel_launch(void* const* d_in, const int* in_sizes, int n_in,
                              void* d_out, int out_size, void* d_ws, size_t ws_size,
                              hipStream_t stream) {
    const float* X[4] = {(const float*)d_in[0], (const float*)d_in[1],
                         (const float*)d_in[2], (const float*)d_in[3]};
    GraphPtrs gp;
    for (int b = 0; b < 4; ++b) {
        gp.r[b] = (const int*)d_in[4 + 3 * b];
        gp.c[b] = (const int*)d_in[5 + 3 * b];
        gp.v[b] = (const float*)d_in[6 + 3 * b];
    }
    const float *w1[4], *b1[4], *w2[4], *b2[4];
    for (int b = 0; b < 4; ++b) {
        w1[b] = (const float*)d_in[16 + 4 * b + 0];
        b1[b] = (const float*)d_in[16 + 4 * b + 1];
        w2[b] = (const float*)d_in[16 + 4 * b + 2];
        b2[b] = (const float*)d_in[16 + 4 * b + 3];
    }
    const int din[4] = {4096, 4096, 4096, 1024};
    const int dh[4] = {512, 512, 512, 256};
    float* out = (float*)d_out;

    char* wsc = (char*)d_ws;
    size_t off = 0;
    auto carve = [&](size_t bytes) {
        void* p = wsc + off;
        off += (bytes + 255) & ~(size_t)255;
        return p;
    };
    int* cnt4 = (int*)carve((size_t)4 * N_NODES * 4);
    int* rs4 = (int*)carve((size_t)4 * (N_NODES + 1) * 4);
    int* cur4 = (int*)carve((size_t)4 * N_NODES * 4);
    unsigned long long* pe4 = (unsigned long long*)carve((size_t)4 * N_EDGES * 8);

    size_t tier1_base = off;
    unsigned short *W1h[4], *W2h[4], *Y1[4], *H1[4];
    for (int b = 0; b < 4; ++b) W1h[b] = (unsigned short*)carve((size_t)dh[b] * din[b] * 2);
    for (int b = 0; b < 4; ++b) W2h[b] = (unsigned short*)carve((size_t)128 * dh[b] * 2);
    for (int b = 0; b < 4; ++b) Y1[b] = (unsigned short*)carve((size_t)N_NODES * dh[b] * 2);
    for (int b = 0; b < 4; ++b) H1[b] = (unsigned short*)carve((size_t)N_NODES * dh[b] * 2);
    unsigned short* Y2all = (unsigned short*)carve((size_t)4 * N_NODES * 128 * 2);
    const bool tier1 = (off <= ws_size);
    unsigned short* Y2s[4];
    if (tier1) {
        for (int b = 0; b < 4; ++b) Y2s[b] = Y2all + (size_t)b * N_NODES * 128;
    } else {
        off = tier1_base;
        unsigned short* w1h = (unsigned short*)carve((size_t)512 * 4096 * 2);
        unsigned short* w2h = (unsigned short*)carve((size_t)128 * 512 * 2);
        unsigned short* y1 = (unsigned short*)carve((size_t)N_NODES * 512 * 2);
        unsigned short* h1 = (unsigned short*)carve((size_t)N_NODES * 512 * 2);
        unsigned short* y2 = (unsigned short*)carve((size_t)N_NODES * 128 * 2);
        for (int b = 0; b < 4; ++b) {
            W1h[b] = w1h; W2h[b] = w2h;
            Y1[b] = y1; H1[b] = h1; Y2s[b] = y2;
        }
    }

    // ---- batched CSR build ----
    hipMemsetAsync(cnt4, 0, (size_t)4 * N_NODES * sizeof(int), stream);
    {
        dim3 g(N_EDGES / 256, 4);
        hist4<<<g, 256, 0, stream>>>(gp, cnt4);
        scan4<<<4, 256, 0, stream>>>(cnt4, rs4, cur4);
        scatter4<<<g, 256, 0, stream>>>(gp, cur4, pe4);
    }

    if (tier1) {
        TransB8 tt;
        for (int b = 0; b < 4; ++b) {
            tt.W[b] = w1[b]; tt.Th[b] = W1h[b]; tt.K[b] = din[b]; tt.N[b] = dh[b];
            tt.W[4 + b] = w2[b]; tt.Th[4 + b] = W2h[b]; tt.K[4 + b] = dh[b]; tt.N[4 + b] = 128;
        }
        tsplit8<<<dim3(128, 16, 8), 256, 0, stream>>>(tt);

        GemmB g1;
        for (int b = 0; b < 4; ++b) {
            g1.A[b] = X[b]; g1.Bh[b] = W1h[b];
            g1.C[b] = Y1[b]; g1.K[b] = din[b]; g1.NT[b] = dh[b] / 256;
        }
        gemm_bf16s<8, 1><<<dim3(64, 2, 4), 256, 0, stream>>>(g1);

        SpmmB s1;
        for (int b = 0; b < 4; ++b) {
            s1.rs[b] = rs4 + (size_t)b * (N_NODES + 1);
            s1.pe[b] = pe4 + (size_t)b * N_EDGES;
            s1.Y[b] = Y1[b]; s1.bi[b] = b1[b]; s1.H[b] = H1[b];
            s1.nc[b] = dh[b];
        }
        spmm_h1x<<<8192, 256, 0, stream>>>(s1);

        GemmB g2;
        for (int b = 0; b < 4; ++b) {
            g2.A[b] = H1[b]; g2.Bh[b] = W2h[b];
            g2.C[b] = Y2s[b]; g2.K[b] = dh[b]; g2.NT[b] = 1;
        }
        gemm_bf16s<4, 0><<<dim3(64, 1, 4), 256, 0, stream>>>(g2);

        Out4 ob;
        for (int b = 0; b < 4; ++b) ob.b2[b] = b2[b];
        spmm_out4<<<N_NODES / 4, 256, 0, stream>>>(rs4, pe4, Y2all, ob, out);
    } else {
        for (int b = 0; b < 4; ++b) {
            TransB8 tt;
            tt.W[0] = w1[b]; tt.Th[0] = W1h[b]; tt.K[0] = din[b]; tt.N[0] = dh[b];
            tsplit8<<<dim3(din[b] / 32, dh[b] / 32, 1), 256, 0, stream>>>(tt);
            GemmB g1;
            g1.A[0] = X[b]; g1.Bh[0] = W1h[b];
            g1.C[0] = Y1[b]; g1.K[0] = din[b]; g1.NT[0] = dh[b] / 256;
            gemm_bf16s<8, 1><<<dim3(64, dh[b] / 256 ? dh[b] / 256 : 1, 1), 256, 0, stream>>>(g1);
            if (dh[b] == 512)
                spmm_h1<512><<<N_NODES / 4, 256, 0, stream>>>(
                    rs4 + (size_t)b * (N_NODES + 1), pe4 + (size_t)b * N_EDGES,
                    Y1[b], b1[b], H1[b]);
            else
                spmm_h1<256><<<N_NODES / 4, 256, 0, stream>>>(
                    rs4 + (size_t)b * (N_NODES + 1), pe4 + (size_t)b * N_EDGES,
                    Y1[b], b1[b], H1[b]);
            TransB8 t2;
            t2.W[0] = w2[b]; t2.Th[0] = W2h[b]; t2.K[0] = dh[b]; t2.N[0] = 128;
            tsplit8<<<dim3(dh[b] / 32, 4, 1), 256, 0, stream>>>(t2);
            GemmB g2;
            g2.A[0] = H1[b]; g2.Bh[0] = W2h[b];
            g2.C[0] = Y2s[b]; g2.K[0] = dh[b]; g2.NT[0] = 1;
            gemm_bf16s<4, 0><<<dim3(64, 1, 1), 256, 0, stream>>>(g2);
            spmm_out1<<<N_NODES / 4, 256, 0, stream>>>(
                rs4 + (size_t)b * (N_NODES + 1), pe4 + (size_t)b * N_EDGES,
                Y2s[b], b2[b], out, b == 0);
        }
    }
}